// Round 1
// baseline (674.048 us; speedup 1.0000x reference)
//
#include <hip/hip_runtime.h>
#include <math.h>

#define DIMN 1024
#define NH 16
#define HD 64
#define CHK 64
#define NB 2
#define SEQ 2048
#define NTOK (NB*SEQ)        // 4096
#define NCHUNK (SEQ/CHK)     // 32
#define GH 16

// ---------------- gate hidden: silu(x @ Wg1 + bg1), (4096,16) ----------------
__global__ __launch_bounds__(256) void k_hidden(const float* __restrict__ x,
    const float* __restrict__ Wg1, const float* __restrict__ bg1,
    float* __restrict__ hid) {
  int idx = blockIdx.x*256 + threadIdx.x;          // 65536 total
  int m = idx >> 4, j = idx & 15;
  const float* xr = x + (size_t)m*DIMN;
  float acc = bg1[j];
  #pragma unroll 8
  for (int k = 0; k < DIMN; ++k) acc = fmaf(xr[k], Wg1[k*GH + j], acc);
  hid[idx] = acc / (1.f + expf(-acc));             // silu
}

// ---------------- alpha = 0.9*sigmoid(hid @ Wg2 + bg2) + 0.1, (4096,1024) ----
__global__ __launch_bounds__(256) void k_alpha(const float* __restrict__ hid,
    const float* __restrict__ Wg2, const float* __restrict__ bg2,
    float* __restrict__ alpha) {
  int idx = blockIdx.x*256 + threadIdx.x;          // 4194304 total
  int m = idx >> 10, n = idx & 1023;
  const float* hr = hid + m*GH;
  float acc = bg2[n];
  #pragma unroll
  for (int j = 0; j < GH; ++j) acc = fmaf(hr[j], Wg2[j*DIMN + n], acc);
  float g = 1.f/(1.f + expf(-acc));
  alpha[idx] = fmaf(0.9f, g, 0.1f);
}

// ---------------- projection GEMM: out = x @ W + b, M=4096 N=1024 K=1024 ----
__global__ __launch_bounds__(256) void k_proj(const float* __restrict__ x,
    const float* __restrict__ W, const float* __restrict__ bias,
    float* __restrict__ out) {
  __shared__ float Xs[16][132];   // [kk][m] (transposed)
  __shared__ float Ws[16][132];   // [kk][n]
  int tid = threadIdx.x;
  int tx = tid & 15, ty = tid >> 4;
  int m0 = blockIdx.y*128, n0 = blockIdx.x*128;
  float acc[8][8] = {};
  for (int kt = 0; kt < DIMN; kt += 16) {
    #pragma unroll
    for (int i = 0; i < 2; ++i) {
      int f4 = tid + i*256;
      int r = f4 >> 2, cg = f4 & 3;
      float4 v = *(const float4*)(x + (size_t)(m0+r)*DIMN + kt + cg*4);
      Xs[cg*4+0][r] = v.x; Xs[cg*4+1][r] = v.y; Xs[cg*4+2][r] = v.z; Xs[cg*4+3][r] = v.w;
    }
    #pragma unroll
    for (int i = 0; i < 2; ++i) {
      int f4 = tid + i*256;
      int r = f4 >> 5, cg = f4 & 31;
      *(float4*)&Ws[r][cg*4] = *(const float4*)(W + (size_t)(kt+r)*DIMN + n0 + cg*4);
    }
    __syncthreads();
    #pragma unroll
    for (int kk = 0; kk < 16; ++kk) {
      float xa[8], wb[8];
      #pragma unroll
      for (int j = 0; j < 8; ++j) xa[j] = Xs[kk][ty*8+j];
      #pragma unroll
      for (int j = 0; j < 8; ++j) wb[j] = Ws[kk][tx*8+j];
      #pragma unroll
      for (int i = 0; i < 8; ++i)
        #pragma unroll
        for (int j = 0; j < 8; ++j)
          acc[i][j] = fmaf(xa[i], wb[j], acc[i][j]);
    }
    __syncthreads();
  }
  #pragma unroll
  for (int i = 0; i < 8; ++i) {
    int m = m0 + ty*8 + i;
    #pragma unroll
    for (int jj = 0; jj < 2; ++jj) {
      int n = n0 + tx*8 + jj*4;
      float4 v;
      v.x = acc[i][jj*4+0] + bias[n+0];
      v.y = acc[i][jj*4+1] + bias[n+1];
      v.z = acc[i][jj*4+2] + bias[n+2];
      v.w = acc[i][jj*4+3] + bias[n+3];
      *(float4*)(out + (size_t)m*DIMN + n) = v;
    }
  }
}

// ---------------- pass 1: chunk boundary states ----------------
// states[bh][n] = S before chunk n.  S' = diag(B) S + sum_i (k_i * suffix_a) v_i^T
__global__ __launch_bounds__(256) void k_states(const float* __restrict__ kbuf,
    const float* __restrict__ vbuf, const float* __restrict__ abuf,
    float* __restrict__ states) {
  __shared__ __align__(16) float kl[CHK][HD+4];
  __shared__ __align__(16) float vl[CHK][HD+4];
  __shared__ __align__(16) float al[CHK][HD+4];
  __shared__ float wprod[4][HD];
  int tid = threadIdx.x;
  int bh = blockIdx.x;
  int b = bh >> 4, h = bh & 15;
  int colbase = h*HD;
  int ti = tid >> 4, te = tid & 15;
  int d0 = ti*4, e0 = te*4;
  int dd = tid & 63, w = tid >> 6;
  float S[4][4] = {};
  for (int n = 0; n < NCHUNK; ++n) {
    size_t rowbase = (size_t)b*SEQ + n*CHK;
    #pragma unroll
    for (int i = 0; i < 4; ++i) {
      int f4 = tid + i*256;
      int r = f4 >> 4, cg = f4 & 15;
      size_t g = (rowbase + r)*DIMN + colbase + cg*4;
      *(float4*)&kl[r][cg*4] = *(const float4*)(kbuf + g);
      *(float4*)&vl[r][cg*4] = *(const float4*)(vbuf + g);
      *(float4*)&al[r][cg*4] = *(const float4*)(abuf + g);
    }
    // store state BEFORE this chunk (registers only, no LDS dependency)
    {
      float* sp = states + (size_t)(bh*NCHUNK + n)*(HD*HD);
      #pragma unroll
      for (int i = 0; i < 4; ++i) {
        float4 v; v.x=S[i][0]; v.y=S[i][1]; v.z=S[i][2]; v.w=S[i][3];
        *(float4*)(sp + (d0+i)*HD + e0) = v;
      }
    }
    __syncthreads();
    // two-level suffix products: kl[i][d] *= prod_{j>i in chunk} a_j[d]
    {
      float sp = 1.f;
      for (int ii = 15; ii >= 0; --ii) {
        int i = w*16 + ii;
        kl[i][dd] *= sp;
        sp *= al[i][dd];
      }
      wprod[w][dd] = sp;
    }
    __syncthreads();
    if (w < 3) {
      float tail = 1.f;
      for (int w2 = w+1; w2 < 4; ++w2) tail *= wprod[w2][dd];
      for (int ii = 0; ii < 16; ++ii) kl[w*16+ii][dd] *= tail;
    }
    __syncthreads();
    // acc = khat^T V  (64x64, K=64)
    float acc[4][4] = {};
    for (int i = 0; i < CHK; ++i) {
      float4 kh = *(const float4*)&kl[i][d0];
      float4 vv = *(const float4*)&vl[i][e0];
      float kf[4] = {kh.x,kh.y,kh.z,kh.w};
      float vf[4] = {vv.x,vv.y,vv.z,vv.w};
      #pragma unroll
      for (int r = 0; r < 4; ++r)
        #pragma unroll
        for (int c = 0; c < 4; ++c)
          acc[r][c] = fmaf(kf[r], vf[c], acc[r][c]);
    }
    #pragma unroll
    for (int r = 0; r < 4; ++r) {
      float Bt = wprod[0][d0+r]*wprod[1][d0+r]*wprod[2][d0+r]*wprod[3][d0+r];
      #pragma unroll
      for (int c = 0; c < 4; ++c)
        S[r][c] = fmaf(Bt, S[r][c], acc[r][c]);
    }
    __syncthreads();
  }
}

// ---------------- pass 2: per-chunk intra softmax + inter (sub-chunked) -----
__global__ __launch_bounds__(256) void k_chunk(const float* __restrict__ qbuf,
    const float* __restrict__ kbuf, const float* __restrict__ vbuf,
    const float* __restrict__ abuf, const float* __restrict__ states,
    float* __restrict__ outp) {
  __shared__ __align__(16) float qt[HD][CHK+4];    // [d][i]
  __shared__ __align__(16) float ktl[HD][CHK+4];   // [d][i]
  __shared__ __align__(16) float vl[CHK][HD+4];    // [s][e]
  __shared__ __align__(16) float lb[CHK+1][HD+4];  // [i][d] cum log2(alpha), exclusive
  __shared__ __align__(16) float scT[CHK][CHK+4];  // [s][i]
  __shared__ __align__(16) float Sl[HD][HD+4];     // [d][e]
  __shared__ __align__(16) float outs[CHK][HD+4];  // [i][e]
  __shared__ float qdec[HD][20];
  __shared__ float kdec[HD][20];
  __shared__ float dg[16][20];
  __shared__ float pm[4][CHK];
  __shared__ float ps[4][CHK];
  __shared__ float seg[4][HD];
  __shared__ float rowsum[CHK];

  int tid = threadIdx.x;
  int bid = blockIdx.x;
  int bh = bid >> 5, n = bid & 31;
  int b = bh >> 4, h = bh & 15;
  int colbase = h*HD;
  size_t rowbase = (size_t)b*SEQ + n*CHK;
  const float* stp = states + (size_t)(bh*NCHUNK + n)*(HD*HD);

  // ---- loads ----
  #pragma unroll
  for (int i = 0; i < 4; ++i) {
    int f4 = tid + i*256;
    int r = f4 >> 4, cg = f4 & 15;
    size_t g = (rowbase + r)*DIMN + colbase + cg*4;
    float4 q4 = *(const float4*)(qbuf + g);
    qt[cg*4+0][r] = q4.x; qt[cg*4+1][r] = q4.y; qt[cg*4+2][r] = q4.z; qt[cg*4+3][r] = q4.w;
    float4 k4 = *(const float4*)(kbuf + g);
    ktl[cg*4+0][r] = k4.x; ktl[cg*4+1][r] = k4.y; ktl[cg*4+2][r] = k4.z; ktl[cg*4+3][r] = k4.w;
    *(float4*)&vl[r][cg*4] = *(const float4*)(vbuf + g);
    float4 a4 = *(const float4*)(abuf + g);
    float4 l4; l4.x = log2f(a4.x); l4.y = log2f(a4.y); l4.z = log2f(a4.z); l4.w = log2f(a4.w);
    *(float4*)&lb[r][cg*4] = l4;
    *(float4*)&Sl[r][cg*4] = *(const float4*)(stp + r*HD + cg*4);
  }
  __syncthreads();

  // ---- exclusive prefix of log2(alpha) along i, per d (two-level) ----
  {
    int d = tid & 63, w = tid >> 6;
    float run = 0.f;
    for (int ii = 0; ii < 16; ++ii) {
      int i = w*16 + ii;
      float t = lb[i][d];
      lb[i][d] = run;
      run += t;
    }
    seg[w][d] = run;
  }
  __syncthreads();
  {
    int d = tid & 63, w = tid >> 6;
    float carry = 0.f;
    for (int w2 = 0; w2 < w; ++w2) carry += seg[w2][d];
    if (w > 0)
      for (int ii = 0; ii < 16; ++ii) lb[w*16+ii][d] += carry;
    if (w == 3) lb[CHK][d] = carry + seg[3][d];
  }
  __syncthreads();

  int ti = tid >> 4, te = tid & 15;

  // ---- QK^T * 0.125 -> scT ----
  {
    int i0 = ti*4, s0 = te*4;
    float acc[4][4] = {};
    for (int d = 0; d < HD; ++d) {
      float4 qv = *(const float4*)&qt[d][i0];
      float4 kv = *(const float4*)&ktl[d][s0];
      float qf[4] = {qv.x,qv.y,qv.z,qv.w};
      float kf[4] = {kv.x,kv.y,kv.z,kv.w};
      #pragma unroll
      for (int a_ = 0; a_ < 4; ++a_)
        #pragma unroll
        for (int b_ = 0; b_ < 4; ++b_)
          acc[a_][b_] = fmaf(qf[a_], kf[b_], acc[a_][b_]);
    }
    #pragma unroll
    for (int b_ = 0; b_ < 4; ++b_) {
      float4 v; v.x = acc[0][b_]*0.125f; v.y = acc[1][b_]*0.125f;
      v.z = acc[2][b_]*0.125f; v.w = acc[3][b_]*0.125f;
      *(float4*)&scT[s0+b_][i0] = v;
    }
  }
  __syncthreads();

  // ---- causal softmax over s<=i (writes exp vals, 0 above diag) ----
  {
    int i = tid & 63, w = tid >> 6;
    float m = -1e30f;
    for (int ss = 0; ss < 16; ++ss) {
      int s = w*16 + ss;
      float v = scT[s][i];
      if (s <= i) m = fmaxf(m, v);
    }
    pm[w][i] = m;
    __syncthreads();
    float M = fmaxf(fmaxf(pm[0][i], pm[1][i]), fmaxf(pm[2][i], pm[3][i]));
    float sum = 0.f;
    for (int ss = 0; ss < 16; ++ss) {
      int s = w*16 + ss;
      float v = scT[s][i];
      float e = (s <= i) ? expf(v - M) : 0.f;
      scT[s][i] = e;
      sum += e;
    }
    ps[w][i] = sum;
    __syncthreads();
    if (w == 0) rowsum[i] = ps[0][i] + ps[1][i] + ps[2][i] + ps[3][i];
  }
  __syncthreads();

  // ---- P@V / rowsum -> outs (intra) ----
  {
    int i0 = ti*4, e0 = te*4;
    float acc[4][4] = {};
    for (int s = 0; s < CHK; ++s) {
      float4 p = *(const float4*)&scT[s][i0];
      float4 vv = *(const float4*)&vl[s][e0];
      float pf[4] = {p.x,p.y,p.z,p.w};
      float vf[4] = {vv.x,vv.y,vv.z,vv.w};
      #pragma unroll
      for (int a_ = 0; a_ < 4; ++a_)
        #pragma unroll
        for (int b_ = 0; b_ < 4; ++b_)
          acc[a_][b_] = fmaf(pf[a_], vf[b_], acc[a_][b_]);
    }
    #pragma unroll
    for (int a_ = 0; a_ < 4; ++a_) {
      float inv = 1.f / rowsum[i0+a_];
      float4 v; v.x = acc[a_][0]*inv; v.y = acc[a_][1]*inv;
      v.z = acc[a_][2]*inv; v.w = acc[a_][3]*inv;
      *(float4*)&outs[i0+a_][e0] = v;
    }
  }
  __syncthreads();

  // ---- inter over 4 sub-blocks of 16 tokens ----
  for (int w = 0; w < 4; ++w) {
    int T = w*16;
    { // qdec / kdec (exp2 of bounded log-diffs, span <= 16 steps)
      int d = tid & 63;
      int ii0 = (tid >> 6)*4;
      float lbT = lb[T][d];
      #pragma unroll
      for (int q_ = 0; q_ < 4; ++q_) {
        int ii = ii0 + q_;
        int i = T + ii;
        qdec[d][ii] = qt[d][i] * exp2f(lb[i][d] - lbT);
        kdec[d][ii] = ktl[d][i] * exp2f(lbT - lb[i+1][d]);
      }
    }
    __syncthreads();
    { // diag scores (strictly causal within sub-block)
      int ii = tid >> 4, ss = tid & 15;
      float acc = 0.f;
      if (ss < ii)
        for (int d = 0; d < HD; ++d)
          acc = fmaf(qdec[d][ii], kdec[d][ss], acc);
      dg[ii][ss] = acc;
    }
    __syncthreads();
    { // cross-term (q~ @ S_T) + diag apply, accumulate into outs
      int ii = tid >> 4, eg = tid & 15;
      int e0 = eg*4;
      float acc[4] = {};
      for (int d = 0; d < HD; ++d) {
        float qd = qdec[d][ii];
        float4 sv = *(const float4*)&Sl[d][e0];
        acc[0] = fmaf(qd, sv.x, acc[0]);
        acc[1] = fmaf(qd, sv.y, acc[1]);
        acc[2] = fmaf(qd, sv.z, acc[2]);
        acc[3] = fmaf(qd, sv.w, acc[3]);
      }
      for (int ss = 0; ss < 16; ++ss) {
        float g = dg[ii][ss];
        float4 vv = *(const float4*)&vl[T+ss][e0];
        acc[0] = fmaf(g, vv.x, acc[0]);
        acc[1] = fmaf(g, vv.y, acc[1]);
        acc[2] = fmaf(g, vv.z, acc[2]);
        acc[3] = fmaf(g, vv.w, acc[3]);
      }
      float4* op = (float4*)&outs[T+ii][e0];
      float4 o = *op;
      o.x += acc[0]; o.y += acc[1]; o.z += acc[2]; o.w += acc[3];
      *op = o;
    }
    __syncthreads();
    if (w < 3) {
      { // khat for sub-state update (decay to sub-block end), reuse kdec
        int d = tid & 63;
        int ii0 = (tid >> 6)*4;
        float lbE = lb[T+16][d];
        #pragma unroll
        for (int q_ = 0; q_ < 4; ++q_) {
          int ii = ii0 + q_;
          kdec[d][ii] = ktl[d][T+ii] * exp2f(lbE - lb[T+ii+1][d]);
        }
      }
      __syncthreads();
      { // Sl = diag(Bsub) Sl + khat^T V
        int d0 = ti*4, e0 = te*4;
        float acc[4][4] = {};
        for (int ss = 0; ss < 16; ++ss) {
          float4 vv = *(const float4*)&vl[T+ss][e0];
          float vf[4] = {vv.x,vv.y,vv.z,vv.w};
          #pragma unroll
          for (int r = 0; r < 4; ++r) {
            float kh = kdec[d0+r][ss];
            #pragma unroll
            for (int c = 0; c < 4; ++c)
              acc[r][c] = fmaf(kh, vf[c], acc[r][c]);
          }
        }
        #pragma unroll
        for (int r = 0; r < 4; ++r) {
          int d = d0 + r;
          float Bsub = exp2f(lb[T+16][d] - lb[T][d]);
          float4* srow = (float4*)&Sl[d][e0];
          float4 s4 = *srow;
          s4.x = fmaf(Bsub, s4.x, acc[r][0]);
          s4.y = fmaf(Bsub, s4.y, acc[r][1]);
          s4.z = fmaf(Bsub, s4.z, acc[r][2]);
          s4.w = fmaf(Bsub, s4.w, acc[r][3]);
          *srow = s4;
        }
      }
      __syncthreads();
    }
  }

  // ---- write out ----
  #pragma unroll
  for (int i = 0; i < 4; ++i) {
    int f4 = tid + i*256;
    int r = f4 >> 4, cg = f4 & 15;
    *(float4*)(outp + (rowbase + r)*DIMN + colbase + cg*4) = *(const float4*)&outs[r][cg*4];
  }
}

extern "C" void kernel_launch(void* const* d_in, const int* in_sizes, int n_in,
                              void* d_out, int out_size, void* d_ws, size_t ws_size,
                              hipStream_t stream) {
  const float* x   = (const float*)d_in[0];
  const float* Wq  = (const float*)d_in[1];
  const float* bq  = (const float*)d_in[2];
  const float* Wk  = (const float*)d_in[3];
  const float* bk  = (const float*)d_in[4];
  const float* Wv  = (const float*)d_in[5];
  const float* bv  = (const float*)d_in[6];
  const float* Wg1 = (const float*)d_in[7];
  const float* bg1 = (const float*)d_in[8];
  const float* Wg2 = (const float*)d_in[9];
  const float* bg2 = (const float*)d_in[10];
  float* out = (float*)d_out;

  float* ws = (float*)d_ws;
  const size_t NT = (size_t)NTOK*DIMN;  // 4194304
  float* qb  = ws;
  float* kb  = ws + NT;
  float* vb  = ws + 2*NT;
  float* ab  = ws + 3*NT;
  float* hid = ws + 4*NT;
  float* st  = ws + 4*NT + (size_t)NTOK*GH;

  k_hidden<<<(NTOK*GH)/256, 256, 0, stream>>>(x, Wg1, bg1, hid);
  dim3 pg(DIMN/128, NTOK/128);
  k_proj<<<pg, 256, 0, stream>>>(x, Wq, bq, qb);
  k_proj<<<pg, 256, 0, stream>>>(x, Wk, bk, kb);
  k_proj<<<pg, 256, 0, stream>>>(x, Wv, bv, vb);
  k_alpha<<<NT/256, 256, 0, stream>>>(hid, Wg2, bg2, ab);
  k_states<<<NB*NH, 256, 0, stream>>>(kb, vb, ab, st);
  k_chunk<<<NB*NH*NCHUNK, 256, 0, stream>>>(qb, kb, vb, ab, st, out);
}

// Round 2
// 324.567 us; speedup vs baseline: 2.0768x; 2.0768x over previous
//
#include <hip/hip_runtime.h>
#include <math.h>

#define DIMN 1024
#define NH 16
#define HD 64
#define CHK 64
#define NB 2
#define SEQ 2048
#define NTOK (NB*SEQ)        // 4096
#define NCHUNK (SEQ/CHK)     // 32
#define GH 16

typedef __bf16 bf16x8 __attribute__((ext_vector_type(8)));
typedef float f32x4 __attribute__((ext_vector_type(4)));

__device__ __forceinline__ unsigned short f2bf(float f) {
  union { float f; unsigned u; } a; a.f = f;
  unsigned r = a.u + 0x7FFFu + ((a.u >> 16) & 1u);
  return (unsigned short)(r >> 16);
}

__device__ __forceinline__ void gload16(const void* g, void* l) {
  __builtin_amdgcn_global_load_lds(
      (const __attribute__((address_space(1))) void*)g,
      (__attribute__((address_space(3))) void*)l, 16, 0, 0);
}

// ---------------- cast x (f32) -> bf16 ----------------
__global__ __launch_bounds__(256) void k_cast_x(const float* __restrict__ x,
    unsigned short* __restrict__ xb) {
  size_t i = (size_t)(blockIdx.x*256 + threadIdx.x)*4;
  float4 v = *(const float4*)(x + i);
  ushort4 o;
  o.x = f2bf(v.x); o.y = f2bf(v.y); o.z = f2bf(v.z); o.w = f2bf(v.w);
  *(ushort4*)(xb + i) = o;
}

// ---------------- cast + transpose W (K x N f32) -> Wt (N x K bf16) --------
__global__ __launch_bounds__(256) void k_cast_wT(const float* __restrict__ W0,
    const float* __restrict__ W1, const float* __restrict__ W2,
    unsigned short* __restrict__ wt) {
  int z = blockIdx.y;
  const float* W = z==0 ? W0 : z==1 ? W1 : W2;
  unsigned short* o = wt + (size_t)z*DIMN*DIMN;
  int idx = blockIdx.x*256 + threadIdx.x;     // 262144
  int n = idx & 1023, k0 = (idx >> 10)*4;
  ushort4 v;
  v.x = f2bf(W[(size_t)(k0+0)*DIMN + n]);
  v.y = f2bf(W[(size_t)(k0+1)*DIMN + n]);
  v.z = f2bf(W[(size_t)(k0+2)*DIMN + n]);
  v.w = f2bf(W[(size_t)(k0+3)*DIMN + n]);
  *(ushort4*)(o + (size_t)n*DIMN + k0) = v;
}

// ---------------- gate hidden: silu(x @ Wg1 + bg1), (4096,16) ----------------
__global__ __launch_bounds__(256) void k_hidden(const float* __restrict__ x,
    const float* __restrict__ Wg1, const float* __restrict__ bg1,
    float* __restrict__ hid) {
  int idx = blockIdx.x*256 + threadIdx.x;          // 65536 total
  int m = idx >> 4, j = idx & 15;
  const float* xr = x + (size_t)m*DIMN;
  float acc = bg1[j];
  #pragma unroll 8
  for (int k = 0; k < DIMN; ++k) acc = fmaf(xr[k], Wg1[k*GH + j], acc);
  hid[idx] = acc / (1.f + expf(-acc));             // silu
}

// ---------------- alpha = 0.9*sigmoid(hid @ Wg2 + bg2) + 0.1 ----------------
__global__ __launch_bounds__(256) void k_alpha(const float* __restrict__ hid,
    const float* __restrict__ Wg2, const float* __restrict__ bg2,
    float* __restrict__ alpha) {
  int idx = blockIdx.x*256 + threadIdx.x;          // 4194304 total
  int m = idx >> 10, n = idx & 1023;
  const float* hr = hid + m*GH;
  float acc = bg2[n];
  #pragma unroll
  for (int j = 0; j < GH; ++j) acc = fmaf(hr[j], Wg2[j*DIMN + n], acc);
  float g = 1.f/(1.f + expf(-acc));
  alpha[idx] = fmaf(0.9f, g, 0.1f);
}

// ---------------- bf16 MFMA projection: out = x @ W + b -----------------
// xb: M x K bf16 row-major.  wt: N x K bf16 row-major (W transposed).
// 128x128 tile, BK=32, 4 waves, double-buffered LDS, global_load_lds 16B.
// XOR swizzle (slot ^= (row>>1)&3) via pre-swizzled global source (rule 21).
__global__ __launch_bounds__(256) void k_projmm(const unsigned short* __restrict__ xb,
    const unsigned short* __restrict__ wt0, const unsigned short* __restrict__ wt1,
    const unsigned short* __restrict__ wt2,
    const float* __restrict__ b0, const float* __restrict__ b1, const float* __restrict__ b2,
    float* __restrict__ o0, float* __restrict__ o1, float* __restrict__ o2) {
  __shared__ unsigned short As[2][128*32];
  __shared__ unsigned short Bs[2][128*32];
  int tid = threadIdx.x;
  int z = blockIdx.z;
  const unsigned short* wt = z==0 ? wt0 : z==1 ? wt1 : wt2;
  const float* bias = z==0 ? b0 : z==1 ? b1 : b2;
  float* out = z==0 ? o0 : z==1 ? o1 : o2;
  int m0 = blockIdx.y*128, n0 = blockIdx.x*128;

  int l = tid & 63;
  int w = tid >> 6;
  int wr = w >> 1, wc = w & 1;
  int lrow = l & 15, kg = l >> 4;

  f32x4 acc[4][4] = {};

  // staging thread->slot map (computed once)
  int r0s = tid >> 2, s0s = tid & 3;
  int r1s = (tid + 256) >> 2;             // s same (tid&3)
  int sg0 = s0s ^ ((r0s >> 1) & 3);
  int sg1 = s0s ^ ((r1s >> 1) & 3);

  #define STAGE(buf, kt) do { \
    int kb_ = (kt)*32; \
    gload16(xb + ((size_t)(m0 + r0s)*DIMN + kb_ + sg0*8), &As[buf][tid*8]); \
    gload16(wt + ((size_t)(n0 + r0s)*DIMN + kb_ + sg0*8), &Bs[buf][tid*8]); \
    gload16(xb + ((size_t)(m0 + r1s)*DIMN + kb_ + sg1*8), &As[buf][(tid+256)*8]); \
    gload16(wt + ((size_t)(n0 + r1s)*DIMN + kb_ + sg1*8), &Bs[buf][(tid+256)*8]); \
  } while (0)

  STAGE(0, 0);
  int buf = 0;
  for (int t = 0; t < DIMN/32; ++t) {
    __syncthreads();                      // staging of t landed (vmcnt drain at barrier)
    if (t+1 < DIMN/32) STAGE(buf^1, t+1);
    union { uint4 u; bf16x8 h; } af[4], bfr[4];
    #pragma unroll
    for (int mf = 0; mf < 4; ++mf) {
      int r = wr*64 + mf*16 + lrow;
      int slot = kg ^ ((r >> 1) & 3);
      af[mf].u = *(const uint4*)&As[buf][r*32 + slot*8];
    }
    #pragma unroll
    for (int nf = 0; nf < 4; ++nf) {
      int r = wc*64 + nf*16 + lrow;
      int slot = kg ^ ((r >> 1) & 3);
      bfr[nf].u = *(const uint4*)&Bs[buf][r*32 + slot*8];
    }
    #pragma unroll
    for (int mf = 0; mf < 4; ++mf)
      #pragma unroll
      for (int nf = 0; nf < 4; ++nf)
        acc[mf][nf] = __builtin_amdgcn_mfma_f32_16x16x32_bf16(
            af[mf].h, bfr[nf].h, acc[mf][nf], 0, 0, 0);
    buf ^= 1;
  }
  #undef STAGE

  // epilogue: C/D layout col=lane&15, row=(lane>>4)*4+reg
  float bv[4];
  #pragma unroll
  for (int nf = 0; nf < 4; ++nf) bv[nf] = bias[n0 + wc*64 + nf*16 + lrow];
  #pragma unroll
  for (int mf = 0; mf < 4; ++mf) {
    int rbase = m0 + wr*64 + mf*16 + kg*4;
    #pragma unroll
    for (int nf = 0; nf < 4; ++nf) {
      int c = n0 + wc*64 + nf*16 + lrow;
      #pragma unroll
      for (int rg = 0; rg < 4; ++rg)
        out[(size_t)(rbase+rg)*DIMN + c] = acc[mf][nf][rg] + bv[nf];
    }
  }
}

// ---------------- pass 1: chunk boundary states ----------------
__global__ __launch_bounds__(256) void k_states(const float* __restrict__ kbuf,
    const float* __restrict__ vbuf, const float* __restrict__ abuf,
    float* __restrict__ states) {
  __shared__ __align__(16) float kl[CHK][HD+4];
  __shared__ __align__(16) float vl[CHK][HD+4];
  __shared__ __align__(16) float al[CHK][HD+4];
  __shared__ float wprod[4][HD];
  int tid = threadIdx.x;
  int bh = blockIdx.x;
  int b = bh >> 4, h = bh & 15;
  int colbase = h*HD;
  int ti = tid >> 4, te = tid & 15;
  int d0 = ti*4, e0 = te*4;
  int dd = tid & 63, w = tid >> 6;
  float S[4][4] = {};
  for (int n = 0; n < NCHUNK; ++n) {
    size_t rowbase = (size_t)b*SEQ + n*CHK;
    #pragma unroll
    for (int i = 0; i < 4; ++i) {
      int f4 = tid + i*256;
      int r = f4 >> 4, cg = f4 & 15;
      size_t g = (rowbase + r)*DIMN + colbase + cg*4;
      *(float4*)&kl[r][cg*4] = *(const float4*)(kbuf + g);
      *(float4*)&vl[r][cg*4] = *(const float4*)(vbuf + g);
      *(float4*)&al[r][cg*4] = *(const float4*)(abuf + g);
    }
    {
      float* sp = states + (size_t)(bh*NCHUNK + n)*(HD*HD);
      #pragma unroll
      for (int i = 0; i < 4; ++i) {
        float4 v; v.x=S[i][0]; v.y=S[i][1]; v.z=S[i][2]; v.w=S[i][3];
        *(float4*)(sp + (d0+i)*HD + e0) = v;
      }
    }
    __syncthreads();
    {
      float sp = 1.f;
      for (int ii = 15; ii >= 0; --ii) {
        int i = w*16 + ii;
        kl[i][dd] *= sp;
        sp *= al[i][dd];
      }
      wprod[w][dd] = sp;
    }
    __syncthreads();
    if (w < 3) {
      float tail = 1.f;
      for (int w2 = w+1; w2 < 4; ++w2) tail *= wprod[w2][dd];
      for (int ii = 0; ii < 16; ++ii) kl[w*16+ii][dd] *= tail;
    }
    __syncthreads();
    float acc[4][4] = {};
    for (int i = 0; i < CHK; ++i) {
      float4 kh = *(const float4*)&kl[i][d0];
      float4 vv = *(const float4*)&vl[i][e0];
      float kf[4] = {kh.x,kh.y,kh.z,kh.w};
      float vf[4] = {vv.x,vv.y,vv.z,vv.w};
      #pragma unroll
      for (int r = 0; r < 4; ++r)
        #pragma unroll
        for (int c = 0; c < 4; ++c)
          acc[r][c] = fmaf(kf[r], vf[c], acc[r][c]);
    }
    #pragma unroll
    for (int r = 0; r < 4; ++r) {
      float Bt = wprod[0][d0+r]*wprod[1][d0+r]*wprod[2][d0+r]*wprod[3][d0+r];
      #pragma unroll
      for (int c = 0; c < 4; ++c)
        S[r][c] = fmaf(Bt, S[r][c], acc[r][c]);
    }
    __syncthreads();
  }
}

// ---------------- pass 2: per-chunk intra softmax + inter (sub-chunked) -----
__global__ __launch_bounds__(256) void k_chunk(const float* __restrict__ qbuf,
    const float* __restrict__ kbuf, const float* __restrict__ vbuf,
    const float* __restrict__ abuf, const float* __restrict__ states,
    float* __restrict__ outp) {
  __shared__ __align__(16) float qt[HD][CHK+4];    // [d][i]
  __shared__ __align__(16) float ktl[HD][CHK+4];   // [d][i]
  __shared__ __align__(16) float vl[CHK][HD+4];    // [s][e]
  __shared__ __align__(16) float lb[CHK+1][HD+4];  // [i][d] cum log2(alpha), exclusive
  __shared__ __align__(16) float scT[CHK][CHK+4];  // [s][i]
  __shared__ __align__(16) float Sl[HD][HD+4];     // [d][e]
  __shared__ __align__(16) float outs[CHK][HD+4];  // [i][e]
  __shared__ float qdec[HD][20];
  __shared__ float kdec[HD][20];
  __shared__ float dg[16][20];
  __shared__ float pm[4][CHK];
  __shared__ float ps[4][CHK];
  __shared__ float seg[4][HD];
  __shared__ float rowsum[CHK];

  int tid = threadIdx.x;
  int bid = blockIdx.x;
  int bh = bid >> 5, n = bid & 31;
  int b = bh >> 4, h = bh & 15;
  int colbase = h*HD;
  size_t rowbase = (size_t)b*SEQ + n*CHK;
  const float* stp = states + (size_t)(bh*NCHUNK + n)*(HD*HD);

  #pragma unroll
  for (int i = 0; i < 4; ++i) {
    int f4 = tid + i*256;
    int r = f4 >> 4, cg = f4 & 15;
    size_t g = (rowbase + r)*DIMN + colbase + cg*4;
    float4 q4 = *(const float4*)(qbuf + g);
    qt[cg*4+0][r] = q4.x; qt[cg*4+1][r] = q4.y; qt[cg*4+2][r] = q4.z; qt[cg*4+3][r] = q4.w;
    float4 k4 = *(const float4*)(kbuf + g);
    ktl[cg*4+0][r] = k4.x; ktl[cg*4+1][r] = k4.y; ktl[cg*4+2][r] = k4.z; ktl[cg*4+3][r] = k4.w;
    *(float4*)&vl[r][cg*4] = *(const float4*)(vbuf + g);
    float4 a4 = *(const float4*)(abuf + g);
    float4 l4; l4.x = log2f(a4.x); l4.y = log2f(a4.y); l4.z = log2f(a4.z); l4.w = log2f(a4.w);
    *(float4*)&lb[r][cg*4] = l4;
    *(float4*)&Sl[r][cg*4] = *(const float4*)(stp + r*HD + cg*4);
  }
  __syncthreads();

  {
    int d = tid & 63, w = tid >> 6;
    float run = 0.f;
    for (int ii = 0; ii < 16; ++ii) {
      int i = w*16 + ii;
      float t = lb[i][d];
      lb[i][d] = run;
      run += t;
    }
    seg[w][d] = run;
  }
  __syncthreads();
  {
    int d = tid & 63, w = tid >> 6;
    float carry = 0.f;
    for (int w2 = 0; w2 < w; ++w2) carry += seg[w2][d];
    if (w > 0)
      for (int ii = 0; ii < 16; ++ii) lb[w*16+ii][d] += carry;
    if (w == 3) lb[CHK][d] = carry + seg[3][d];
  }
  __syncthreads();

  int ti = tid >> 4, te = tid & 15;

  {
    int i0 = ti*4, s0 = te*4;
    float acc[4][4] = {};
    for (int d = 0; d < HD; ++d) {
      float4 qv = *(const float4*)&qt[d][i0];
      float4 kv = *(const float4*)&ktl[d][s0];
      float qf[4] = {qv.x,qv.y,qv.z,qv.w};
      float kf[4] = {kv.x,kv.y,kv.z,kv.w};
      #pragma unroll
      for (int a_ = 0; a_ < 4; ++a_)
        #pragma unroll
        for (int b_ = 0; b_ < 4; ++b_)
          acc[a_][b_] = fmaf(qf[a_], kf[b_], acc[a_][b_]);
    }
    #pragma unroll
    for (int b_ = 0; b_ < 4; ++b_) {
      float4 v; v.x = acc[0][b_]*0.125f; v.y = acc[1][b_]*0.125f;
      v.z = acc[2][b_]*0.125f; v.w = acc[3][b_]*0.125f;
      *(float4*)&scT[s0+b_][i0] = v;
    }
  }
  __syncthreads();

  {
    int i = tid & 63, w = tid >> 6;
    float m = -1e30f;
    for (int ss = 0; ss < 16; ++ss) {
      int s = w*16 + ss;
      float v = scT[s][i];
      if (s <= i) m = fmaxf(m, v);
    }
    pm[w][i] = m;
    __syncthreads();
    float M = fmaxf(fmaxf(pm[0][i], pm[1][i]), fmaxf(pm[2][i], pm[3][i]));
    float sum = 0.f;
    for (int ss = 0; ss < 16; ++ss) {
      int s = w*16 + ss;
      float v = scT[s][i];
      float e = (s <= i) ? expf(v - M) : 0.f;
      scT[s][i] = e;
      sum += e;
    }
    ps[w][i] = sum;
    __syncthreads();
    if (w == 0) rowsum[i] = ps[0][i] + ps[1][i] + ps[2][i] + ps[3][i];
  }
  __syncthreads();

  {
    int i0 = ti*4, e0 = te*4;
    float acc[4][4] = {};
    for (int s = 0; s < CHK; ++s) {
      float4 p = *(const float4*)&scT[s][i0];
      float4 vv = *(const float4*)&vl[s][e0];
      float pf[4] = {p.x,p.y,p.z,p.w};
      float vf[4] = {vv.x,vv.y,vv.z,vv.w};
      #pragma unroll
      for (int a_ = 0; a_ < 4; ++a_)
        #pragma unroll
        for (int b_ = 0; b_ < 4; ++b_)
          acc[a_][b_] = fmaf(pf[a_], vf[b_], acc[a_][b_]);
    }
    #pragma unroll
    for (int a_ = 0; a_ < 4; ++a_) {
      float inv = 1.f / rowsum[i0+a_];
      float4 v; v.x = acc[a_][0]*inv; v.y = acc[a_][1]*inv;
      v.z = acc[a_][2]*inv; v.w = acc[a_][3]*inv;
      *(float4*)&outs[i0+a_][e0] = v;
    }
  }
  __syncthreads();

  for (int w = 0; w < 4; ++w) {
    int T = w*16;
    {
      int d = tid & 63;
      int ii0 = (tid >> 6)*4;
      float lbT = lb[T][d];
      #pragma unroll
      for (int q_ = 0; q_ < 4; ++q_) {
        int ii = ii0 + q_;
        int i = T + ii;
        qdec[d][ii] = qt[d][i] * exp2f(lb[i][d] - lbT);
        kdec[d][ii] = ktl[d][i] * exp2f(lbT - lb[i+1][d]);
      }
    }
    __syncthreads();
    {
      int ii = tid >> 4, ss = tid & 15;
      float acc = 0.f;
      if (ss < ii)
        for (int d = 0; d < HD; ++d)
          acc = fmaf(qdec[d][ii], kdec[d][ss], acc);
      dg[ii][ss] = acc;
    }
    __syncthreads();
    {
      int ii = tid >> 4, eg = tid & 15;
      int e0 = eg*4;
      float acc[4] = {};
      for (int d = 0; d < HD; ++d) {
        float qd = qdec[d][ii];
        float4 sv = *(const float4*)&Sl[d][e0];
        acc[0] = fmaf(qd, sv.x, acc[0]);
        acc[1] = fmaf(qd, sv.y, acc[1]);
        acc[2] = fmaf(qd, sv.z, acc[2]);
        acc[3] = fmaf(qd, sv.w, acc[3]);
      }
      for (int ss = 0; ss < 16; ++ss) {
        float g = dg[ii][ss];
        float4 vv = *(const float4*)&vl[T+ss][e0];
        acc[0] = fmaf(g, vv.x, acc[0]);
        acc[1] = fmaf(g, vv.y, acc[1]);
        acc[2] = fmaf(g, vv.z, acc[2]);
        acc[3] = fmaf(g, vv.w, acc[3]);
      }
      float4* op = (float4*)&outs[T+ii][e0];
      float4 o = *op;
      o.x += acc[0]; o.y += acc[1]; o.z += acc[2]; o.w += acc[3];
      *op = o;
    }
    __syncthreads();
    if (w < 3) {
      {
        int d = tid & 63;
        int ii0 = (tid >> 6)*4;
        float lbE = lb[T+16][d];
        #pragma unroll
        for (int q_ = 0; q_ < 4; ++q_) {
          int ii = ii0 + q_;
          kdec[d][ii] = ktl[d][T+ii] * exp2f(lbE - lb[T+ii+1][d]);
        }
      }
      __syncthreads();
      {
        int d0 = ti*4, e0 = te*4;
        float acc[4][4] = {};
        for (int ss = 0; ss < 16; ++ss) {
          float4 vv = *(const float4*)&vl[T+ss][e0];
          float vf[4] = {vv.x,vv.y,vv.z,vv.w};
          #pragma unroll
          for (int r = 0; r < 4; ++r) {
            float kh = kdec[d0+r][ss];
            #pragma unroll
            for (int c = 0; c < 4; ++c)
              acc[r][c] = fmaf(kh, vf[c], acc[r][c]);
          }
        }
        #pragma unroll
        for (int r = 0; r < 4; ++r) {
          int d = d0 + r;
          float Bsub = exp2f(lb[T+16][d] - lb[T][d]);
          float4* srow = (float4*)&Sl[d][e0];
          float4 s4 = *srow;
          s4.x = fmaf(Bsub, s4.x, acc[r][0]);
          s4.y = fmaf(Bsub, s4.y, acc[r][1]);
          s4.z = fmaf(Bsub, s4.z, acc[r][2]);
          s4.w = fmaf(Bsub, s4.w, acc[r][3]);
          *srow = s4;
        }
      }
      __syncthreads();
    }
  }

  #pragma unroll
  for (int i = 0; i < 4; ++i) {
    int f4 = tid + i*256;
    int r = f4 >> 4, cg = f4 & 15;
    *(float4*)(outp + (rowbase + r)*DIMN + colbase + cg*4) = *(const float4*)&outs[r][cg*4];
  }
}

extern "C" void kernel_launch(void* const* d_in, const int* in_sizes, int n_in,
                              void* d_out, int out_size, void* d_ws, size_t ws_size,
                              hipStream_t stream) {
  const float* x   = (const float*)d_in[0];
  const float* Wq  = (const float*)d_in[1];
  const float* bq  = (const float*)d_in[2];
  const float* Wk  = (const float*)d_in[3];
  const float* bk  = (const float*)d_in[4];
  const float* Wv  = (const float*)d_in[5];
  const float* bv  = (const float*)d_in[6];
  const float* Wg1 = (const float*)d_in[7];
  const float* bg1 = (const float*)d_in[8];
  const float* Wg2 = (const float*)d_in[9];
  const float* bg2 = (const float*)d_in[10];
  float* out = (float*)d_out;

  float* ws = (float*)d_ws;
  const size_t NT = (size_t)NTOK*DIMN;  // 4194304
  float* qb  = ws;
  float* kb  = ws + NT;
  float* vb  = ws + 2*NT;
  float* ab  = ws + 3*NT;
  float* hid = ws + 4*NT;
  float* st  = ws + 4*NT + (size_t)NTOK*GH;
  unsigned short* xb = (unsigned short*)(st + (size_t)NB*NH*NCHUNK*HD*HD);
  unsigned short* wt = xb + NT;                 // 3 x 1024x1024 bf16

  k_cast_x<<<NT/(4*256), 256, 0, stream>>>(x, xb);
  k_cast_wT<<<dim3(DIMN*DIMN/(4*256), 3), 256, 0, stream>>>(Wq, Wk, Wv, wt);
  k_hidden<<<(NTOK*GH)/256, 256, 0, stream>>>(x, Wg1, bg1, hid);
  k_projmm<<<dim3(DIMN/128, NTOK/128, 3), 256, 0, stream>>>(
      xb, wt, wt + (size_t)DIMN*DIMN, wt + 2*(size_t)DIMN*DIMN,
      bq, bk, bv, qb, kb, vb);
  k_alpha<<<NT/256, 256, 0, stream>>>(hid, Wg2, bg2, ab);
  k_states<<<NB*NH, 256, 0, stream>>>(kb, vb, ab, st);
  k_chunk<<<NB*NH*NCHUNK, 256, 0, stream>>>(qb, kb, vb, ab, st, out);
}

// Round 3
// 231.367 us; speedup vs baseline: 2.9133x; 1.4028x over previous
//
#include <hip/hip_runtime.h>
#include <math.h>

#define DIMN 1024
#define NH 16
#define HD 64
#define CHK 64
#define NB 2
#define SEQ 2048
#define NTOK (NB*SEQ)        // 4096
#define NCHUNK (SEQ/CHK)     // 32
#define GH 16

typedef __bf16 bf16x8 __attribute__((ext_vector_type(8)));
typedef float f32x4 __attribute__((ext_vector_type(4)));

__device__ __forceinline__ unsigned short f2bf(float f) {
  union { float f; unsigned u; } a; a.f = f;
  unsigned r = a.u + 0x7FFFu + ((a.u >> 16) & 1u);
  return (unsigned short)(r >> 16);
}

__device__ __forceinline__ void gload16(const void* g, void* l) {
  __builtin_amdgcn_global_load_lds(
      (const __attribute__((address_space(1))) void*)g,
      (__attribute__((address_space(3))) void*)l, 16, 0, 0);
}

// ---------------- cast x (f32) -> bf16 ----------------
__global__ __launch_bounds__(256) void k_cast_x(const float* __restrict__ x,
    unsigned short* __restrict__ xb) {
  size_t i = (size_t)(blockIdx.x*256 + threadIdx.x)*4;
  float4 v = *(const float4*)(x + i);
  ushort4 o;
  o.x = f2bf(v.x); o.y = f2bf(v.y); o.z = f2bf(v.z); o.w = f2bf(v.w);
  *(ushort4*)(xb + i) = o;
}

// ---------------- cast + transpose W (K x N f32) -> Wt (N x K bf16) --------
__global__ __launch_bounds__(256) void k_cast_wT(const float* __restrict__ W0,
    const float* __restrict__ W1, const float* __restrict__ W2,
    unsigned short* __restrict__ wt) {
  int z = blockIdx.y;
  const float* W = z==0 ? W0 : z==1 ? W1 : W2;
  unsigned short* o = wt + (size_t)z*DIMN*DIMN;
  int idx = blockIdx.x*256 + threadIdx.x;     // 262144
  int n = idx & 1023, k0 = (idx >> 10)*4;
  ushort4 v;
  v.x = f2bf(W[(size_t)(k0+0)*DIMN + n]);
  v.y = f2bf(W[(size_t)(k0+1)*DIMN + n]);
  v.z = f2bf(W[(size_t)(k0+2)*DIMN + n]);
  v.w = f2bf(W[(size_t)(k0+3)*DIMN + n]);
  *(ushort4*)(o + (size_t)n*DIMN + k0) = v;
}

// ---------------- gate hidden: silu(x @ Wg1 + bg1), (4096,16) ----------------
__global__ __launch_bounds__(256) void k_hidden(const float* __restrict__ x,
    const float* __restrict__ Wg1, const float* __restrict__ bg1,
    float* __restrict__ hid) {
  int idx = blockIdx.x*256 + threadIdx.x;          // 65536 total
  int m = idx >> 4, j = idx & 15;
  const float* xr = x + (size_t)m*DIMN;
  float acc = bg1[j];
  #pragma unroll 8
  for (int k = 0; k < DIMN; ++k) acc = fmaf(xr[k], Wg1[k*GH + j], acc);
  hid[idx] = acc / (1.f + expf(-acc));             // silu
}

// ---------------- alpha = 0.9*sigmoid(hid @ Wg2 + bg2) + 0.1 ----------------
__global__ __launch_bounds__(256) void k_alpha(const float* __restrict__ hid,
    const float* __restrict__ Wg2, const float* __restrict__ bg2,
    float* __restrict__ alpha) {
  int idx = blockIdx.x*256 + threadIdx.x;          // 4194304 total
  int m = idx >> 10, n = idx & 1023;
  const float* hr = hid + m*GH;
  float acc = bg2[n];
  #pragma unroll
  for (int j = 0; j < GH; ++j) acc = fmaf(hr[j], Wg2[j*DIMN + n], acc);
  float g = 1.f/(1.f + expf(-acc));
  alpha[idx] = fmaf(0.9f, g, 0.1f);
}

// ---------------- bf16 MFMA projection: out = x @ W + b -----------------
__global__ __launch_bounds__(256) void k_projmm(const unsigned short* __restrict__ xb,
    const unsigned short* __restrict__ wt0, const unsigned short* __restrict__ wt1,
    const unsigned short* __restrict__ wt2,
    const float* __restrict__ b0, const float* __restrict__ b1, const float* __restrict__ b2,
    float* __restrict__ o0, float* __restrict__ o1, float* __restrict__ o2) {
  __shared__ unsigned short As[2][128*32];
  __shared__ unsigned short Bs[2][128*32];
  int tid = threadIdx.x;
  int z = blockIdx.z;
  const unsigned short* wt = z==0 ? wt0 : z==1 ? wt1 : wt2;
  const float* bias = z==0 ? b0 : z==1 ? b1 : b2;
  float* out = z==0 ? o0 : z==1 ? o1 : o2;
  int m0 = blockIdx.y*128, n0 = blockIdx.x*128;

  int l = tid & 63;
  int w = tid >> 6;
  int wr = w >> 1, wc = w & 1;
  int lrow = l & 15, kg = l >> 4;

  f32x4 acc[4][4] = {};

  int r0s = tid >> 2, s0s = tid & 3;
  int r1s = (tid + 256) >> 2;
  int sg0 = s0s ^ ((r0s >> 1) & 3);
  int sg1 = s0s ^ ((r1s >> 1) & 3);

  #define STAGE(buf, kt) do { \
    int kb_ = (kt)*32; \
    gload16(xb + ((size_t)(m0 + r0s)*DIMN + kb_ + sg0*8), &As[buf][tid*8]); \
    gload16(wt + ((size_t)(n0 + r0s)*DIMN + kb_ + sg0*8), &Bs[buf][tid*8]); \
    gload16(xb + ((size_t)(m0 + r1s)*DIMN + kb_ + sg1*8), &As[buf][(tid+256)*8]); \
    gload16(wt + ((size_t)(n0 + r1s)*DIMN + kb_ + sg1*8), &Bs[buf][(tid+256)*8]); \
  } while (0)

  STAGE(0, 0);
  int buf = 0;
  for (int t = 0; t < DIMN/32; ++t) {
    __syncthreads();
    if (t+1 < DIMN/32) STAGE(buf^1, t+1);
    union { uint4 u; bf16x8 h; } af[4], bfr[4];
    #pragma unroll
    for (int mf = 0; mf < 4; ++mf) {
      int r = wr*64 + mf*16 + lrow;
      int slot = kg ^ ((r >> 1) & 3);
      af[mf].u = *(const uint4*)&As[buf][r*32 + slot*8];
    }
    #pragma unroll
    for (int nf = 0; nf < 4; ++nf) {
      int r = wc*64 + nf*16 + lrow;
      int slot = kg ^ ((r >> 1) & 3);
      bfr[nf].u = *(const uint4*)&Bs[buf][r*32 + slot*8];
    }
    #pragma unroll
    for (int mf = 0; mf < 4; ++mf)
      #pragma unroll
      for (int nf = 0; nf < 4; ++nf)
        acc[mf][nf] = __builtin_amdgcn_mfma_f32_16x16x32_bf16(
            af[mf].h, bfr[nf].h, acc[mf][nf], 0, 0, 0);
    buf ^= 1;
  }
  #undef STAGE

  float bv[4];
  #pragma unroll
  for (int nf = 0; nf < 4; ++nf) bv[nf] = bias[n0 + wc*64 + nf*16 + lrow];
  #pragma unroll
  for (int mf = 0; mf < 4; ++mf) {
    int rbase = m0 + wr*64 + mf*16 + kg*4;
    #pragma unroll
    for (int nf = 0; nf < 4; ++nf) {
      int c = n0 + wc*64 + nf*16 + lrow;
      #pragma unroll
      for (int rg = 0; rg < 4; ++rg)
        out[(size_t)(rbase+rg)*DIMN + c] = acc[mf][nf][rg] + bv[nf];
    }
  }
}

// ---------------- pass 1a (parallel): per-chunk increment G_n and decay B_n --
// G[bh][n][d][e] = sum_i k_i[d]*suffix_a_i[d] * v_i[e];  Bv[bh][n][d] = prod_i a_i[d]
__global__ __launch_bounds__(256) void k_ginc(const float* __restrict__ kbuf,
    const float* __restrict__ vbuf, const float* __restrict__ abuf,
    float* __restrict__ G, float* __restrict__ Bv) {
  __shared__ __align__(16) float kl[CHK][HD+4];
  __shared__ __align__(16) float vl[CHK][HD+4];
  __shared__ __align__(16) float al[CHK][HD+4];
  __shared__ float wprod[4][HD];
  int tid = threadIdx.x;
  int bid = blockIdx.x;                 // bh*NCHUNK + n
  int bh = bid >> 5, n = bid & 31;
  int b = bh >> 4, h = bh & 15;
  int colbase = h*HD;
  size_t rowbase = (size_t)b*SEQ + n*CHK;
  int dd = tid & 63, w = tid >> 6;

  #pragma unroll
  for (int i = 0; i < 4; ++i) {
    int f4 = tid + i*256;
    int r = f4 >> 4, cg = f4 & 15;
    size_t g = (rowbase + r)*DIMN + colbase + cg*4;
    *(float4*)&kl[r][cg*4] = *(const float4*)(kbuf + g);
    *(float4*)&vl[r][cg*4] = *(const float4*)(vbuf + g);
    *(float4*)&al[r][cg*4] = *(const float4*)(abuf + g);
  }
  __syncthreads();
  {
    float sp = 1.f;
    for (int ii = 15; ii >= 0; --ii) {
      int i = w*16 + ii;
      kl[i][dd] *= sp;
      sp *= al[i][dd];
    }
    wprod[w][dd] = sp;
  }
  __syncthreads();
  if (w < 3) {
    float tail = 1.f;
    for (int w2 = w+1; w2 < 4; ++w2) tail *= wprod[w2][dd];
    for (int ii = 0; ii < 16; ++ii) kl[w*16+ii][dd] *= tail;
  }
  if (tid < HD)
    Bv[(size_t)bid*HD + tid] = wprod[0][tid]*wprod[1][tid]*wprod[2][tid]*wprod[3][tid];
  __syncthreads();

  int ti = tid >> 4, te = tid & 15;
  int d0 = ti*4, e0 = te*4;
  float acc[4][4] = {};
  for (int i = 0; i < CHK; ++i) {
    float4 kh = *(const float4*)&kl[i][d0];
    float4 vv = *(const float4*)&vl[i][e0];
    float kf[4] = {kh.x,kh.y,kh.z,kh.w};
    float vf[4] = {vv.x,vv.y,vv.z,vv.w};
    #pragma unroll
    for (int r = 0; r < 4; ++r)
      #pragma unroll
      for (int c = 0; c < 4; ++c)
        acc[r][c] = fmaf(kf[r], vf[c], acc[r][c]);
  }
  float* gp = G + (size_t)bid*(HD*HD);
  #pragma unroll
  for (int r = 0; r < 4; ++r) {
    float4 v; v.x=acc[r][0]; v.y=acc[r][1]; v.z=acc[r][2]; v.w=acc[r][3];
    *(float4*)(gp + (d0+r)*HD + e0) = v;
  }
}

// ---------------- pass 1b (parallel scan): in-place G -> states -------------
// Each thread owns one (bh,d,e): scalar recurrence s_{n+1} = B[n][d]*s_n + G[n][d][e],
// writing the pre-state into the same slot (in place).
__global__ __launch_bounds__(256) void k_scan(float* __restrict__ buf,
    const float* __restrict__ Bv) {
  int idx = blockIdx.x*256 + threadIdx.x;   // 131072 = 32*64*64
  int e = idx & 63, d = (idx >> 6) & 63, bh = idx >> 12;
  float* gp = buf + (size_t)bh*NCHUNK*HD*HD + d*HD + e;
  const float* bp = Bv + (size_t)bh*NCHUNK*HD + d;
  float s = 0.f;
  float g = gp[0], bb = bp[0];
  #pragma unroll
  for (int n = 0; n < NCHUNK; ++n) {
    float gn = 0.f, bn = 0.f;
    if (n+1 < NCHUNK) { gn = gp[(n+1)*(HD*HD)]; bn = bp[(n+1)*HD]; }
    gp[n*(HD*HD)] = s;
    s = fmaf(bb, s, g);
    g = gn; bb = bn;
  }
}

// ---------------- pass 2: per-chunk intra softmax + inter (sub-chunked) -----
__global__ __launch_bounds__(256) void k_chunk(const float* __restrict__ qbuf,
    const float* __restrict__ kbuf, const float* __restrict__ vbuf,
    const float* __restrict__ abuf, const float* __restrict__ states,
    float* __restrict__ outp) {
  __shared__ __align__(16) float qt[HD][CHK+4];    // [d][i]
  __shared__ __align__(16) float ktl[HD][CHK+4];   // [d][i]
  __shared__ __align__(16) float vl[CHK][HD+4];    // [s][e]
  __shared__ __align__(16) float lb[CHK+1][HD+4];  // [i][d] cum log2(alpha), exclusive
  __shared__ __align__(16) float scT[CHK][CHK+4];  // [s][i]
  __shared__ __align__(16) float Sl[HD][HD+4];     // [d][e]
  __shared__ __align__(16) float outs[CHK][HD+4];  // [i][e]
  __shared__ float qdec[HD][20];
  __shared__ float kdec[HD][20];
  __shared__ float dg[16][20];
  __shared__ float pm[4][CHK];
  __shared__ float ps[4][CHK];
  __shared__ float seg[4][HD];
  __shared__ float rowsum[CHK];

  int tid = threadIdx.x;
  int bid = blockIdx.x;
  int bh = bid >> 5, n = bid & 31;
  int b = bh >> 4, h = bh & 15;
  int colbase = h*HD;
  size_t rowbase = (size_t)b*SEQ + n*CHK;
  const float* stp = states + (size_t)(bh*NCHUNK + n)*(HD*HD);

  #pragma unroll
  for (int i = 0; i < 4; ++i) {
    int f4 = tid + i*256;
    int r = f4 >> 4, cg = f4 & 15;
    size_t g = (rowbase + r)*DIMN + colbase + cg*4;
    float4 q4 = *(const float4*)(qbuf + g);
    qt[cg*4+0][r] = q4.x; qt[cg*4+1][r] = q4.y; qt[cg*4+2][r] = q4.z; qt[cg*4+3][r] = q4.w;
    float4 k4 = *(const float4*)(kbuf + g);
    ktl[cg*4+0][r] = k4.x; ktl[cg*4+1][r] = k4.y; ktl[cg*4+2][r] = k4.z; ktl[cg*4+3][r] = k4.w;
    *(float4*)&vl[r][cg*4] = *(const float4*)(vbuf + g);
    float4 a4 = *(const float4*)(abuf + g);
    float4 l4; l4.x = log2f(a4.x); l4.y = log2f(a4.y); l4.z = log2f(a4.z); l4.w = log2f(a4.w);
    *(float4*)&lb[r][cg*4] = l4;
    *(float4*)&Sl[r][cg*4] = *(const float4*)(stp + r*HD + cg*4);
  }
  __syncthreads();

  {
    int d = tid & 63, w = tid >> 6;
    float run = 0.f;
    for (int ii = 0; ii < 16; ++ii) {
      int i = w*16 + ii;
      float t = lb[i][d];
      lb[i][d] = run;
      run += t;
    }
    seg[w][d] = run;
  }
  __syncthreads();
  {
    int d = tid & 63, w = tid >> 6;
    float carry = 0.f;
    for (int w2 = 0; w2 < w; ++w2) carry += seg[w2][d];
    if (w > 0)
      for (int ii = 0; ii < 16; ++ii) lb[w*16+ii][d] += carry;
    if (w == 3) lb[CHK][d] = carry + seg[3][d];
  }
  __syncthreads();

  int ti = tid >> 4, te = tid & 15;

  {
    int i0 = ti*4, s0 = te*4;
    float acc[4][4] = {};
    for (int d = 0; d < HD; ++d) {
      float4 qv = *(const float4*)&qt[d][i0];
      float4 kv = *(const float4*)&ktl[d][s0];
      float qf[4] = {qv.x,qv.y,qv.z,qv.w};
      float kf[4] = {kv.x,kv.y,kv.z,kv.w};
      #pragma unroll
      for (int a_ = 0; a_ < 4; ++a_)
        #pragma unroll
        for (int b_ = 0; b_ < 4; ++b_)
          acc[a_][b_] = fmaf(qf[a_], kf[b_], acc[a_][b_]);
    }
    #pragma unroll
    for (int b_ = 0; b_ < 4; ++b_) {
      float4 v; v.x = acc[0][b_]*0.125f; v.y = acc[1][b_]*0.125f;
      v.z = acc[2][b_]*0.125f; v.w = acc[3][b_]*0.125f;
      *(float4*)&scT[s0+b_][i0] = v;
    }
  }
  __syncthreads();

  {
    int i = tid & 63, w = tid >> 6;
    float m = -1e30f;
    for (int ss = 0; ss < 16; ++ss) {
      int s = w*16 + ss;
      float v = scT[s][i];
      if (s <= i) m = fmaxf(m, v);
    }
    pm[w][i] = m;
    __syncthreads();
    float M = fmaxf(fmaxf(pm[0][i], pm[1][i]), fmaxf(pm[2][i], pm[3][i]));
    float sum = 0.f;
    for (int ss = 0; ss < 16; ++ss) {
      int s = w*16 + ss;
      float v = scT[s][i];
      float e = (s <= i) ? expf(v - M) : 0.f;
      scT[s][i] = e;
      sum += e;
    }
    ps[w][i] = sum;
    __syncthreads();
    if (w == 0) rowsum[i] = ps[0][i] + ps[1][i] + ps[2][i] + ps[3][i];
  }
  __syncthreads();

  {
    int i0 = ti*4, e0 = te*4;
    float acc[4][4] = {};
    for (int s = 0; s < CHK; ++s) {
      float4 p = *(const float4*)&scT[s][i0];
      float4 vv = *(const float4*)&vl[s][e0];
      float pf[4] = {p.x,p.y,p.z,p.w};
      float vf[4] = {vv.x,vv.y,vv.z,vv.w};
      #pragma unroll
      for (int a_ = 0; a_ < 4; ++a_)
        #pragma unroll
        for (int b_ = 0; b_ < 4; ++b_)
          acc[a_][b_] = fmaf(pf[a_], vf[b_], acc[a_][b_]);
    }
    #pragma unroll
    for (int a_ = 0; a_ < 4; ++a_) {
      float inv = 1.f / rowsum[i0+a_];
      float4 v; v.x = acc[a_][0]*inv; v.y = acc[a_][1]*inv;
      v.z = acc[a_][2]*inv; v.w = acc[a_][3]*inv;
      *(float4*)&outs[i0+a_][e0] = v;
    }
  }
  __syncthreads();

  for (int w = 0; w < 4; ++w) {
    int T = w*16;
    {
      int d = tid & 63;
      int ii0 = (tid >> 6)*4;
      float lbT = lb[T][d];
      #pragma unroll
      for (int q_ = 0; q_ < 4; ++q_) {
        int ii = ii0 + q_;
        int i = T + ii;
        qdec[d][ii] = qt[d][i] * exp2f(lb[i][d] - lbT);
        kdec[d][ii] = ktl[d][i] * exp2f(lbT - lb[i+1][d]);
      }
    }
    __syncthreads();
    {
      int ii = tid >> 4, ss = tid & 15;
      float acc = 0.f;
      if (ss < ii)
        for (int d = 0; d < HD; ++d)
          acc = fmaf(qdec[d][ii], kdec[d][ss], acc);
      dg[ii][ss] = acc;
    }
    __syncthreads();
    {
      int ii = tid >> 4, eg = tid & 15;
      int e0 = eg*4;
      float acc[4] = {};
      for (int d = 0; d < HD; ++d) {
        float qd = qdec[d][ii];
        float4 sv = *(const float4*)&Sl[d][e0];
        acc[0] = fmaf(qd, sv.x, acc[0]);
        acc[1] = fmaf(qd, sv.y, acc[1]);
        acc[2] = fmaf(qd, sv.z, acc[2]);
        acc[3] = fmaf(qd, sv.w, acc[3]);
      }
      for (int ss = 0; ss < 16; ++ss) {
        float g = dg[ii][ss];
        float4 vv = *(const float4*)&vl[T+ss][e0];
        acc[0] = fmaf(g, vv.x, acc[0]);
        acc[1] = fmaf(g, vv.y, acc[1]);
        acc[2] = fmaf(g, vv.z, acc[2]);
        acc[3] = fmaf(g, vv.w, acc[3]);
      }
      float4* op = (float4*)&outs[T+ii][e0];
      float4 o = *op;
      o.x += acc[0]; o.y += acc[1]; o.z += acc[2]; o.w += acc[3];
      *op = o;
    }
    __syncthreads();
    if (w < 3) {
      {
        int d = tid & 63;
        int ii0 = (tid >> 6)*4;
        float lbE = lb[T+16][d];
        #pragma unroll
        for (int q_ = 0; q_ < 4; ++q_) {
          int ii = ii0 + q_;
          kdec[d][ii] = ktl[d][T+ii] * exp2f(lbE - lb[T+ii+1][d]);
        }
      }
      __syncthreads();
      {
        int d0 = ti*4, e0 = te*4;
        float acc[4][4] = {};
        for (int ss = 0; ss < 16; ++ss) {
          float4 vv = *(const float4*)&vl[T+ss][e0];
          float vf[4] = {vv.x,vv.y,vv.z,vv.w};
          #pragma unroll
          for (int r = 0; r < 4; ++r) {
            float kh = kdec[d0+r][ss];
            #pragma unroll
            for (int c = 0; c < 4; ++c)
              acc[r][c] = fmaf(kh, vf[c], acc[r][c]);
          }
        }
        #pragma unroll
        for (int r = 0; r < 4; ++r) {
          int d = d0 + r;
          float Bsub = exp2f(lb[T+16][d] - lb[T][d]);
          float4* srow = (float4*)&Sl[d][e0];
          float4 s4 = *srow;
          s4.x = fmaf(Bsub, s4.x, acc[r][0]);
          s4.y = fmaf(Bsub, s4.y, acc[r][1]);
          s4.z = fmaf(Bsub, s4.z, acc[r][2]);
          s4.w = fmaf(Bsub, s4.w, acc[r][3]);
          *srow = s4;
        }
      }
      __syncthreads();
    }
  }

  #pragma unroll
  for (int i = 0; i < 4; ++i) {
    int f4 = tid + i*256;
    int r = f4 >> 4, cg = f4 & 15;
    *(float4*)(outp + (rowbase + r)*DIMN + colbase + cg*4) = *(const float4*)&outs[r][cg*4];
  }
}

extern "C" void kernel_launch(void* const* d_in, const int* in_sizes, int n_in,
                              void* d_out, int out_size, void* d_ws, size_t ws_size,
                              hipStream_t stream) {
  const float* x   = (const float*)d_in[0];
  const float* Wq  = (const float*)d_in[1];
  const float* bq  = (const float*)d_in[2];
  const float* Wk  = (const float*)d_in[3];
  const float* bk  = (const float*)d_in[4];
  const float* Wv  = (const float*)d_in[5];
  const float* bv  = (const float*)d_in[6];
  const float* Wg1 = (const float*)d_in[7];
  const float* bg1 = (const float*)d_in[8];
  const float* Wg2 = (const float*)d_in[9];
  const float* bg2 = (const float*)d_in[10];
  float* out = (float*)d_out;

  float* ws = (float*)d_ws;
  const size_t NT = (size_t)NTOK*DIMN;  // 4194304
  float* qb  = ws;
  float* kb  = ws + NT;
  float* vb  = ws + 2*NT;
  float* ab  = ws + 3*NT;
  float* hid = ws + 4*NT;
  float* st  = ws + 4*NT + (size_t)NTOK*GH;              // G then (in-place) states
  float* Bv  = st + (size_t)NB*NH*NCHUNK*HD*HD;          // 1024*64
  unsigned short* xb = (unsigned short*)(Bv + (size_t)NB*NH*NCHUNK*HD);
  unsigned short* wt = xb + NT;                          // 3 x 1024x1024 bf16

  k_cast_x<<<NT/(4*256), 256, 0, stream>>>(x, xb);
  k_cast_wT<<<dim3(DIMN*DIMN/(4*256), 3), 256, 0, stream>>>(Wq, Wk, Wv, wt);
  k_hidden<<<(NTOK*GH)/256, 256, 0, stream>>>(x, Wg1, bg1, hid);
  k_projmm<<<dim3(DIMN/128, NTOK/128, 3), 256, 0, stream>>>(
      xb, wt, wt + (size_t)DIMN*DIMN, wt + 2*(size_t)DIMN*DIMN,
      bq, bk, bv, qb, kb, vb);
  k_alpha<<<NT/256, 256, 0, stream>>>(hid, Wg2, bg2, ab);
  k_ginc<<<NB*NH*NCHUNK, 256, 0, stream>>>(kb, vb, ab, st, Bv);
  k_scan<<<(NB*NH*HD*HD)/256, 256, 0, stream>>>(st, Bv);
  k_chunk<<<NB*NH*NCHUNK, 256, 0, stream>>>(qb, kb, vb, ab, st, out);
}

// Round 4
// 165.442 us; speedup vs baseline: 4.0742x; 1.3985x over previous
//
#include <hip/hip_runtime.h>
#include <math.h>

#define DIMN 1024
#define NH 16
#define HD 64
#define CHK 64
#define NB 2
#define SEQ 2048
#define NTOK (NB*SEQ)        // 4096
#define NCHUNK (SEQ/CHK)     // 32
#define GH 16

typedef __bf16 bf16x8 __attribute__((ext_vector_type(8)));
typedef float f32x4 __attribute__((ext_vector_type(4)));
typedef unsigned short u16x4 __attribute__((ext_vector_type(4)));

__device__ __forceinline__ unsigned short f2bf(float f) {
  union { float f; unsigned u; } a; a.f = f;
  unsigned r = a.u + 0x7FFFu + ((a.u >> 16) & 1u);
  return (unsigned short)(r >> 16);
}
__device__ __forceinline__ float bf2f(unsigned short v) {
  union { unsigned u; float f; } a; a.u = ((unsigned)v) << 16;
  return a.f;
}

__device__ __forceinline__ void gload16(const void* g, void* l) {
  __builtin_amdgcn_global_load_lds(
      (const __attribute__((address_space(1))) void*)g,
      (__attribute__((address_space(3))) void*)l, 16, 0, 0);
}

// ---------------- cast x (f32) -> bf16 ----------------
__global__ __launch_bounds__(256) void k_cast_x(const float* __restrict__ x,
    unsigned short* __restrict__ xb) {
  size_t i = (size_t)(blockIdx.x*256 + threadIdx.x)*4;
  float4 v = *(const float4*)(x + i);
  ushort4 o;
  o.x = f2bf(v.x); o.y = f2bf(v.y); o.z = f2bf(v.z); o.w = f2bf(v.w);
  *(ushort4*)(xb + i) = o;
}

// ---------------- cast + transpose W (K x N f32) -> Wt (N x K bf16) --------
__global__ __launch_bounds__(256) void k_cast_wT(const float* __restrict__ W0,
    const float* __restrict__ W1, const float* __restrict__ W2,
    unsigned short* __restrict__ wt) {
  int z = blockIdx.y;
  const float* W = z==0 ? W0 : z==1 ? W1 : W2;
  unsigned short* o = wt + (size_t)z*DIMN*DIMN;
  int idx = blockIdx.x*256 + threadIdx.x;     // 262144
  int n = idx & 1023, k0 = (idx >> 10)*4;
  ushort4 v;
  v.x = f2bf(W[(size_t)(k0+0)*DIMN + n]);
  v.y = f2bf(W[(size_t)(k0+1)*DIMN + n]);
  v.z = f2bf(W[(size_t)(k0+2)*DIMN + n]);
  v.w = f2bf(W[(size_t)(k0+3)*DIMN + n]);
  *(ushort4*)(o + (size_t)n*DIMN + k0) = v;
}

// ---------------- gate hidden: silu(x @ Wg1 + bg1), (4096,16) ----------------
__global__ __launch_bounds__(256) void k_hidden(const float* __restrict__ x,
    const float* __restrict__ Wg1, const float* __restrict__ bg1,
    float* __restrict__ hid) {
  int idx = blockIdx.x*256 + threadIdx.x;          // 65536 total
  int m = idx >> 4, j = idx & 15;
  const float* xr = x + (size_t)m*DIMN;
  float acc = bg1[j];
  #pragma unroll 8
  for (int k = 0; k < DIMN; ++k) acc = fmaf(xr[k], Wg1[k*GH + j], acc);
  hid[idx] = acc / (1.f + expf(-acc));             // silu
}

// ---------------- alpha = 0.9*sigmoid(hid @ Wg2 + bg2) + 0.1 ----------------
__global__ __launch_bounds__(256) void k_alpha(const float* __restrict__ hid,
    const float* __restrict__ Wg2, const float* __restrict__ bg2,
    float* __restrict__ alpha) {
  int idx = blockIdx.x*256 + threadIdx.x;          // 4194304 total
  int m = idx >> 10, n = idx & 1023;
  const float* hr = hid + m*GH;
  float acc = bg2[n];
  #pragma unroll
  for (int j = 0; j < GH; ++j) acc = fmaf(hr[j], Wg2[j*DIMN + n], acc);
  float g = 1.f/(1.f + expf(-acc));
  alpha[idx] = fmaf(0.9f, g, 0.1f);
}

// ---------------- bf16 MFMA projection: out = x @ W + b -----------------
__global__ __launch_bounds__(256) void k_projmm(const unsigned short* __restrict__ xb,
    const unsigned short* __restrict__ wt0, const unsigned short* __restrict__ wt1,
    const unsigned short* __restrict__ wt2,
    const float* __restrict__ b0, const float* __restrict__ b1, const float* __restrict__ b2,
    float* __restrict__ o0, float* __restrict__ o1, float* __restrict__ o2) {
  __shared__ unsigned short As[2][128*32];
  __shared__ unsigned short Bs[2][128*32];
  int tid = threadIdx.x;
  int z = blockIdx.z;
  const unsigned short* wt = z==0 ? wt0 : z==1 ? wt1 : wt2;
  const float* bias = z==0 ? b0 : z==1 ? b1 : b2;
  float* out = z==0 ? o0 : z==1 ? o1 : o2;
  int m0 = blockIdx.y*128, n0 = blockIdx.x*128;

  int l = tid & 63;
  int w = tid >> 6;
  int wr = w >> 1, wc = w & 1;
  int lrow = l & 15, kg = l >> 4;

  f32x4 acc[4][4] = {};

  int r0s = tid >> 2, s0s = tid & 3;
  int r1s = (tid + 256) >> 2;
  int sg0 = s0s ^ ((r0s >> 1) & 3);
  int sg1 = s0s ^ ((r1s >> 1) & 3);

  #define STAGE(buf, kt) do { \
    int kb_ = (kt)*32; \
    gload16(xb + ((size_t)(m0 + r0s)*DIMN + kb_ + sg0*8), &As[buf][tid*8]); \
    gload16(wt + ((size_t)(n0 + r0s)*DIMN + kb_ + sg0*8), &Bs[buf][tid*8]); \
    gload16(xb + ((size_t)(m0 + r1s)*DIMN + kb_ + sg1*8), &As[buf][(tid+256)*8]); \
    gload16(wt + ((size_t)(n0 + r1s)*DIMN + kb_ + sg1*8), &Bs[buf][(tid+256)*8]); \
  } while (0)

  STAGE(0, 0);
  int buf = 0;
  for (int t = 0; t < DIMN/32; ++t) {
    __syncthreads();
    if (t+1 < DIMN/32) STAGE(buf^1, t+1);
    union { uint4 u; bf16x8 h; } af[4], bfr[4];
    #pragma unroll
    for (int mf = 0; mf < 4; ++mf) {
      int r = wr*64 + mf*16 + lrow;
      int slot = kg ^ ((r >> 1) & 3);
      af[mf].u = *(const uint4*)&As[buf][r*32 + slot*8];
    }
    #pragma unroll
    for (int nf = 0; nf < 4; ++nf) {
      int r = wc*64 + nf*16 + lrow;
      int slot = kg ^ ((r >> 1) & 3);
      bfr[nf].u = *(const uint4*)&Bs[buf][r*32 + slot*8];
    }
    #pragma unroll
    for (int mf = 0; mf < 4; ++mf)
      #pragma unroll
      for (int nf = 0; nf < 4; ++nf)
        acc[mf][nf] = __builtin_amdgcn_mfma_f32_16x16x32_bf16(
            af[mf].h, bfr[nf].h, acc[mf][nf], 0, 0, 0);
    buf ^= 1;
  }
  #undef STAGE

  float bv[4];
  #pragma unroll
  for (int nf = 0; nf < 4; ++nf) bv[nf] = bias[n0 + wc*64 + nf*16 + lrow];
  #pragma unroll
  for (int mf = 0; mf < 4; ++mf) {
    int rbase = m0 + wr*64 + mf*16 + kg*4;
    #pragma unroll
    for (int nf = 0; nf < 4; ++nf) {
      int c = n0 + wc*64 + nf*16 + lrow;
      #pragma unroll
      for (int rg = 0; rg < 4; ++rg)
        out[(size_t)(rbase+rg)*DIMN + c] = acc[mf][nf][rg] + bv[nf];
    }
  }
}

// ---------------- pass 1a (parallel): per-chunk increment G_n and decay B_n --
__global__ __launch_bounds__(256) void k_ginc(const float* __restrict__ kbuf,
    const float* __restrict__ vbuf, const float* __restrict__ abuf,
    float* __restrict__ G, float* __restrict__ Bv) {
  __shared__ __align__(16) float kl[CHK][HD+4];
  __shared__ __align__(16) float vl[CHK][HD+4];
  __shared__ __align__(16) float al[CHK][HD+4];
  __shared__ float wprod[4][HD];
  int tid = threadIdx.x;
  int bid = blockIdx.x;                 // bh*NCHUNK + n
  int bh = bid >> 5, n = bid & 31;
  int b = bh >> 4, h = bh & 15;
  int colbase = h*HD;
  size_t rowbase = (size_t)b*SEQ + n*CHK;
  int dd = tid & 63, w = tid >> 6;

  #pragma unroll
  for (int i = 0; i < 4; ++i) {
    int f4 = tid + i*256;
    int r = f4 >> 4, cg = f4 & 15;
    size_t g = (rowbase + r)*DIMN + colbase + cg*4;
    *(float4*)&kl[r][cg*4] = *(const float4*)(kbuf + g);
    *(float4*)&vl[r][cg*4] = *(const float4*)(vbuf + g);
    *(float4*)&al[r][cg*4] = *(const float4*)(abuf + g);
  }
  __syncthreads();
  {
    float sp = 1.f;
    for (int ii = 15; ii >= 0; --ii) {
      int i = w*16 + ii;
      kl[i][dd] *= sp;
      sp *= al[i][dd];
    }
    wprod[w][dd] = sp;
  }
  __syncthreads();
  if (w < 3) {
    float tail = 1.f;
    for (int w2 = w+1; w2 < 4; ++w2) tail *= wprod[w2][dd];
    for (int ii = 0; ii < 16; ++ii) kl[w*16+ii][dd] *= tail;
  }
  if (tid < HD)
    Bv[(size_t)bid*HD + tid] = wprod[0][tid]*wprod[1][tid]*wprod[2][tid]*wprod[3][tid];
  __syncthreads();

  int ti = tid >> 4, te = tid & 15;
  int d0 = ti*4, e0 = te*4;
  float acc[4][4] = {};
  for (int i = 0; i < CHK; ++i) {
    float4 kh = *(const float4*)&kl[i][d0];
    float4 vv = *(const float4*)&vl[i][e0];
    float kf[4] = {kh.x,kh.y,kh.z,kh.w};
    float vf[4] = {vv.x,vv.y,vv.z,vv.w};
    #pragma unroll
    for (int r = 0; r < 4; ++r)
      #pragma unroll
      for (int c = 0; c < 4; ++c)
        acc[r][c] = fmaf(kf[r], vf[c], acc[r][c]);
  }
  float* gp = G + (size_t)bid*(HD*HD);
  #pragma unroll
  for (int r = 0; r < 4; ++r) {
    float4 v; v.x=acc[r][0]; v.y=acc[r][1]; v.z=acc[r][2]; v.w=acc[r][3];
    *(float4*)(gp + (d0+r)*HD + e0) = v;
  }
}

// ---------------- pass 1b (parallel scan): in-place G -> states -------------
__global__ __launch_bounds__(256) void k_scan(float* __restrict__ buf,
    const float* __restrict__ Bv) {
  int idx = blockIdx.x*256 + threadIdx.x;   // 131072 = 32*64*64
  int e = idx & 63, d = (idx >> 6) & 63, bh = idx >> 12;
  float* gp = buf + (size_t)bh*NCHUNK*HD*HD + d*HD + e;
  const float* bp = Bv + (size_t)bh*NCHUNK*HD + d;
  float s = 0.f;
  float g = gp[0], bb = bp[0];
  #pragma unroll
  for (int n = 0; n < NCHUNK; ++n) {
    float gn = 0.f, bn = 0.f;
    if (n+1 < NCHUNK) { gn = gp[(n+1)*(HD*HD)]; bn = bp[(n+1)*HD]; }
    gp[n*(HD*HD)] = s;
    s = fmaf(bb, s, g);
    g = gn; bb = bn;
  }
}

// ---------------- pass 2: MFMA per-chunk intra softmax + inter (sub=32) -----
// LDS bf16 rows padded to 72 (16B-aligned), lb f32 rows 68.
__global__ __launch_bounds__(256) void k_chunk(const float* __restrict__ qbuf,
    const float* __restrict__ kbuf, const float* __restrict__ vbuf,
    const float* __restrict__ abuf, const float* __restrict__ states,
    float* __restrict__ outp) {
  __shared__ __align__(16) unsigned short qb16[64*72];
  __shared__ __align__(16) unsigned short kb16[64*72];
  __shared__ __align__(16) unsigned short vT[64*72];     // [e][s]
  __shared__ __align__(16) unsigned short Pl[64*72];     // [i][s]
  __shared__ __align__(16) unsigned short Swt[2][64*72]; // [e][d] states (T=0, T=32)
  __shared__ __align__(16) float lb[65*68];              // [i][d] exclusive prefix log2(alpha)
  __shared__ __align__(16) unsigned short dgs[4][16*40]; // per-wave dg A staging
  __shared__ float seg[4][64];

  const int tid = threadIdx.x;
  const int bid = blockIdx.x;
  const int bh = bid >> 5, n = bid & 31;
  const int b = bh >> 4, h = bh & 15;
  const int colbase = h*HD;
  const size_t rowbase = (size_t)b*SEQ + n*CHK;
  const float* stp = states + (size_t)(bh*NCHUNK + n)*(HD*HD);

  // ---- loads (+ transposes, casts) ----
  #pragma unroll
  for (int i = 0; i < 4; ++i) {
    int f4 = tid + i*256;
    int r = f4 >> 4, cg = f4 & 15, c0 = cg*4;
    size_t g = (rowbase + r)*DIMN + colbase + c0;
    f32x4 q4 = *(const f32x4*)(qbuf + g);
    f32x4 k4 = *(const f32x4*)(kbuf + g);
    f32x4 v4 = *(const f32x4*)(vbuf + g);
    f32x4 a4 = *(const f32x4*)(abuf + g);
    f32x4 s4 = *(const f32x4*)(stp + r*HD + c0);
    u16x4 qo, ko;
    f32x4 l4;
    #pragma unroll
    for (int j = 0; j < 4; ++j) {
      qo[j] = f2bf(q4[j]); ko[j] = f2bf(k4[j]);
      vT[(c0+j)*72 + r] = f2bf(v4[j]);
      Swt[0][(c0+j)*72 + r] = f2bf(s4[j]);
      l4[j] = log2f(a4[j]);
    }
    *(u16x4*)&qb16[r*72 + c0] = qo;
    *(u16x4*)&kb16[r*72 + c0] = ko;
    *(f32x4*)&lb[r*68 + c0] = l4;
  }
  __syncthreads();

  // ---- exclusive prefix of log2(alpha) along i, per d ----
  {
    int d = tid & 63, ww = tid >> 6;
    float run = 0.f;
    #pragma unroll
    for (int ii = 0; ii < 16; ++ii) {
      int i = ww*16 + ii;
      float t = lb[i*68 + d];
      lb[i*68 + d] = run;
      run += t;
    }
    seg[ww][d] = run;
  }
  __syncthreads();
  {
    int d = tid & 63, ww = tid >> 6;
    float carry = 0.f;
    for (int w2 = 0; w2 < ww; ++w2) carry += seg[w2][d];
    if (ww > 0)
      for (int ii = 0; ii < 16; ++ii) lb[(ww*16+ii)*68 + d] += carry;
    if (ww == 3) lb[64*68 + d] = carry + seg[3][d];
  }
  __syncthreads();

  const int l = tid & 63, w = tid >> 6;
  const int lr = l & 15, lg = l >> 4;
  const int ks = lg*8;
  const int arow = w*16 + lr;            // A-frag row (wave tile rows 16w..16w+15)

  union FB { uint4 u; bf16x8 h; unsigned short s[8]; };

  // ---- QK^T (MFMA) ----
  FB qa0, qa1;
  qa0.u = *(const uint4*)&qb16[arow*72 + ks];
  qa1.u = *(const uint4*)&qb16[arow*72 + 32 + ks];
  f32x4 sc[4];
  #pragma unroll
  for (int nf = 0; nf < 4; ++nf) {
    FB b0, b1;
    b0.u = *(const uint4*)&kb16[(nf*16+lr)*72 + ks];
    b1.u = *(const uint4*)&kb16[(nf*16+lr)*72 + 32 + ks];
    f32x4 z = {0.f,0.f,0.f,0.f};
    z = __builtin_amdgcn_mfma_f32_16x16x32_bf16(qa0.h, b0.h, z, 0,0,0);
    z = __builtin_amdgcn_mfma_f32_16x16x32_bf16(qa1.h, b1.h, z, 0,0,0);
    sc[nf] = z;
  }

  // ---- in-register causal softmax (rows = w*16 + lg*4 + rg) ----
  float rmax[4] = {-3e38f,-3e38f,-3e38f,-3e38f};
  #pragma unroll
  for (int nf = 0; nf < 4; ++nf) {
    int col = nf*16 + lr;
    #pragma unroll
    for (int rg = 0; rg < 4; ++rg) {
      int row = w*16 + lg*4 + rg;
      float v = sc[nf][rg]*0.125f;
      if (col > row) v = -1e30f;
      sc[nf][rg] = v;
      rmax[rg] = fmaxf(rmax[rg], v);
    }
  }
  #pragma unroll
  for (int m = 1; m <= 8; m <<= 1)
    #pragma unroll
    for (int rg = 0; rg < 4; ++rg)
      rmax[rg] = fmaxf(rmax[rg], __shfl_xor(rmax[rg], m));
  float rsum[4] = {0.f,0.f,0.f,0.f};
  #pragma unroll
  for (int nf = 0; nf < 4; ++nf)
    #pragma unroll
    for (int rg = 0; rg < 4; ++rg) {
      float e = exp2f((sc[nf][rg] - rmax[rg])*1.44269504f);
      sc[nf][rg] = e;
      rsum[rg] += e;
    }
  #pragma unroll
  for (int m = 1; m <= 8; m <<= 1)
    #pragma unroll
    for (int rg = 0; rg < 4; ++rg)
      rsum[rg] += __shfl_xor(rsum[rg], m);
  #pragma unroll
  for (int nf = 0; nf < 4; ++nf)
    #pragma unroll
    for (int rg = 0; rg < 4; ++rg)
      Pl[(w*16 + lg*4 + rg)*72 + nf*16 + lr] = f2bf(sc[nf][rg]);
  float inv[4];
  #pragma unroll
  for (int rg = 0; rg < 4; ++rg) inv[rg] = 1.f/rsum[rg];
  __syncthreads();

  // ---- intra = P@V / rowsum (MFMA) ----
  f32x4 acc[4];
  {
    FB p0, p1;
    p0.u = *(const uint4*)&Pl[arow*72 + ks];
    p1.u = *(const uint4*)&Pl[arow*72 + 32 + ks];
    #pragma unroll
    for (int nf = 0; nf < 4; ++nf) {
      FB v0, v1;
      v0.u = *(const uint4*)&vT[(nf*16+lr)*72 + ks];
      v1.u = *(const uint4*)&vT[(nf*16+lr)*72 + 32 + ks];
      f32x4 z = {0.f,0.f,0.f,0.f};
      z = __builtin_amdgcn_mfma_f32_16x16x32_bf16(p0.h, v0.h, z, 0,0,0);
      z = __builtin_amdgcn_mfma_f32_16x16x32_bf16(p1.h, v1.h, z, 0,0,0);
      #pragma unroll
      for (int rg = 0; rg < 4; ++rg)
        acc[nf][rg] = z[rg]*inv[rg];
    }
  }

  // ---- state update: S1 = diag(exp2(lb32)) S0 + sum_{s<32} kupd_s v_s^T ----
  {
    int dA = arow;                       // A row = d
    float lb32 = lb[32*68 + dA];
    FB ku;
    #pragma unroll
    for (int j = 0; j < 8; ++j) {
      int s = ks + j;                    // s in 0..31
      float kv = bf2f(kb16[s*72 + dA]);
      ku.s[j] = f2bf(kv * exp2f(lb32 - lb[(s+1)*68 + dA]));
    }
    int d0 = w*16 + lg*4;
    float bs[4];
    #pragma unroll
    for (int rg = 0; rg < 4; ++rg) bs[rg] = exp2f(lb[32*68 + d0 + rg]);
    #pragma unroll
    for (int nf = 0; nf < 4; ++nf) {
      int e = nf*16 + lr;
      FB vv;
      vv.u = *(const uint4*)&vT[e*72 + ks];
      f32x4 z = {0.f,0.f,0.f,0.f};
      z = __builtin_amdgcn_mfma_f32_16x16x32_bf16(ku.h, vv.h, z, 0,0,0);
      u16x4 s0v = *(const u16x4*)&Swt[0][e*72 + d0];
      u16x4 s1v;
      #pragma unroll
      for (int rg = 0; rg < 4; ++rg)
        s1v[rg] = f2bf(z[rg] + bs[rg]*bf2f(s0v[rg]));
      *(u16x4*)&Swt[1][e*72 + d0] = s1v;
    }
  }
  __syncthreads();

  // ---- inter: cross (qdec @ S_T^T) + strict-lower diag, per wave ----
  {
    const int T = (w >= 2) ? 32 : 0;
    const unsigned short* Ssel = (w >= 2) ? &Swt[1][0] : &Swt[0][0];
    // qdec A-frags (2 k-steps over d)
    FB qd[2];
    #pragma unroll
    for (int kst = 0; kst < 2; ++kst) {
      int ds = kst*32 + ks;
      f32x4 lbi0 = *(const f32x4*)&lb[arow*68 + ds];
      f32x4 lbi1 = *(const f32x4*)&lb[arow*68 + ds + 4];
      f32x4 lbt0 = *(const f32x4*)&lb[T*68 + ds];
      f32x4 lbt1 = *(const f32x4*)&lb[T*68 + ds + 4];
      FB qr;
      qr.u = *(const uint4*)&qb16[arow*72 + ds];
      #pragma unroll
      for (int j = 0; j < 4; ++j) {
        qd[kst].s[j]   = f2bf(bf2f(qr.s[j])   * exp2f(lbi0[j] - lbt0[j]));
        qd[kst].s[4+j] = f2bf(bf2f(qr.s[4+j]) * exp2f(lbi1[j] - lbt1[j]));
      }
    }
    // cross into acc
    #pragma unroll
    for (int nf = 0; nf < 4; ++nf) {
      FB s0f, s1f;
      s0f.u = *(const uint4*)&Ssel[(nf*16+lr)*72 + ks];
      s1f.u = *(const uint4*)&Ssel[(nf*16+lr)*72 + 32 + ks];
      acc[nf] = __builtin_amdgcn_mfma_f32_16x16x32_bf16(qd[0].h, s0f.h, acc[nf], 0,0,0);
      acc[nf] = __builtin_amdgcn_mfma_f32_16x16x32_bf16(qd[1].h, s1f.h, acc[nf], 0,0,0);
    }
    // diag: dg = qdec @ kdec^T (per-sub-block strict lower)
    const int nb_ = (w & 1) ? 2 : 1;
    f32x4 dgc[2] = {{0.f,0.f,0.f,0.f},{0.f,0.f,0.f,0.f}};
    #pragma unroll
    for (int bf_ = 0; bf_ < 2; ++bf_) {
      if (bf_ < nb_) {
        int s = T + bf_*16 + lr;         // B row = s (local ss = bf_*16+lr)
        f32x4 z = {0.f,0.f,0.f,0.f};
        #pragma unroll
        for (int kst = 0; kst < 2; ++kst) {
          int ds = kst*32 + ks;
          f32x4 lbt0 = *(const f32x4*)&lb[T*68 + ds];
          f32x4 lbt1 = *(const f32x4*)&lb[T*68 + ds + 4];
          f32x4 lbs0 = *(const f32x4*)&lb[(s+1)*68 + ds];
          f32x4 lbs1 = *(const f32x4*)&lb[(s+1)*68 + ds + 4];
          FB kr, kd;
          kr.u = *(const uint4*)&kb16[s*72 + ds];
          #pragma unroll
          for (int j = 0; j < 4; ++j) {
            kd.s[j]   = f2bf(bf2f(kr.s[j])   * exp2f(lbt0[j] - lbs0[j]));
            kd.s[4+j] = f2bf(bf2f(kr.s[4+j]) * exp2f(lbt1[j] - lbs1[j]));
          }
          z = __builtin_amdgcn_mfma_f32_16x16x32_bf16(qd[kst].h, kd.h, z, 0,0,0);
        }
        dgc[bf_] = z;
      }
    }
    // mask (ss < ii) + stage dg as bf16 A-operand
    int iis = (w & 1)*16 + lg*4;         // ii_sub of reg rows
    #pragma unroll
    for (int bf_ = 0; bf_ < 2; ++bf_) {
      #pragma unroll
      for (int rg = 0; rg < 4; ++rg) {
        int ssu = bf_*16 + lr;
        float v = (bf_ < nb_ && ssu < iis + rg) ? dgc[bf_][rg] : 0.f;
        dgs[w][(lg*4 + rg)*40 + bf_*16 + lr] = f2bf(v);
      }
    }
    // dg @ V (K=32 local)
    FB dga;
    dga.u = *(const uint4*)&dgs[w][lr*40 + ks];
    #pragma unroll
    for (int nf = 0; nf < 4; ++nf) {
      FB vv;
      vv.u = *(const uint4*)&vT[(nf*16+lr)*72 + T + ks];
      acc[nf] = __builtin_amdgcn_mfma_f32_16x16x32_bf16(dga.h, vv.h, acc[nf], 0,0,0);
    }
  }

  // ---- store ----
  #pragma unroll
  for (int nf = 0; nf < 4; ++nf)
    #pragma unroll
    for (int rg = 0; rg < 4; ++rg)
      outp[(rowbase + w*16 + lg*4 + rg)*DIMN + colbase + nf*16 + lr] = acc[nf][rg];
}

extern "C" void kernel_launch(void* const* d_in, const int* in_sizes, int n_in,
                              void* d_out, int out_size, void* d_ws, size_t ws_size,
                              hipStream_t stream) {
  const float* x   = (const float*)d_in[0];
  const float* Wq  = (const float*)d_in[1];
  const float* bq  = (const float*)d_in[2];
  const float* Wk  = (const float*)d_in[3];
  const float* bk  = (const float*)d_in[4];
  const float* Wv  = (const float*)d_in[5];
  const float* bv  = (const float*)d_in[6];
  const float* Wg1 = (const float*)d_in[7];
  const float* bg1 = (const float*)d_in[8];
  const float* Wg2 = (const float*)d_in[9];
  const float* bg2 = (const float*)d_in[10];
  float* out = (float*)d_out;

  float* ws = (float*)d_ws;
  const size_t NT = (size_t)NTOK*DIMN;  // 4194304
  float* qb  = ws;
  float* kb  = ws + NT;
  float* vb  = ws + 2*NT;
  float* ab  = ws + 3*NT;
  float* hid = ws + 4*NT;
  float* st  = ws + 4*NT + (size_t)NTOK*GH;              // G then (in-place) states
  float* Bv  = st + (size_t)NB*NH*NCHUNK*HD*HD;          // 1024*64
  unsigned short* xb = (unsigned short*)(Bv + (size_t)NB*NH*NCHUNK*HD);
  unsigned short* wt = xb + NT;                          // 3 x 1024x1024 bf16

  k_cast_x<<<NT/(4*256), 256, 0, stream>>>(x, xb);
  k_cast_wT<<<dim3(DIMN*DIMN/(4*256), 3), 256, 0, stream>>>(Wq, Wk, Wv, wt);
  k_hidden<<<(NTOK*GH)/256, 256, 0, stream>>>(x, Wg1, bg1, hid);
  k_projmm<<<dim3(DIMN/128, NTOK/128, 3), 256, 0, stream>>>(
      xb, wt, wt + (size_t)DIMN*DIMN, wt + 2*(size_t)DIMN*DIMN,
      bq, bk, bv, qb, kb, vb);
  k_alpha<<<NT/256, 256, 0, stream>>>(hid, Wg2, bg2, ab);
  k_ginc<<<NB*NH*NCHUNK, 256, 0, stream>>>(kb, vb, ab, st, Bv);
  k_scan<<<(NB*NH*HD*HD)/256, 256, 0, stream>>>(st, Bv);
  k_chunk<<<NB*NH*NCHUNK, 256, 0, stream>>>(qb, kb, vb, ab, st, out);
}